// Round 8
// baseline (345.853 us; speedup 1.0000x reference)
//
#include <hip/hip_runtime.h>
#include <math.h>

#define N_NODES 100000
#define N_EDGES 1280000
#define DIM 64
#define N_GRAPHS 1000
#define BN_EPS 1e-5f
#define NB 392            // buckets = dst>>8; 392*256 = 100352 >= N_NODES
#define P1B 1024          // pass-1 histogram blocks (R20: 256->1024, 4 blocks/CU)
#define P1E 1250          // edges per pass-1 block; 1024*1250 = 1.28M exactly
#define SB 400            // stats blocks (400*250 = 100k rows, contiguous spans)
#define WIN 128           // edges per gather wave window
#define NWIN (N_EDGES / WIN)   // 10000
#define NSLOT 32          // BN-stat partial slots

// ---- bf16 helpers (top 16 bits of fp32, RTN) ----
__device__ __forceinline__ unsigned int bf16_rtn2(float a, float b) {
    unsigned int ua = __float_as_uint(a);
    unsigned int ub = __float_as_uint(b);
    ua = (ua + 0x7FFFu + ((ua >> 16) & 1u)) >> 16;
    ub = (ub + 0x7FFFu + ((ub >> 16) & 1u)) >> 16;
    return ua | (ub << 16);
}
__device__ __forceinline__ unsigned short bf16r(float a) {
    unsigned int u = __float_as_uint(a);
    return (unsigned short)((u + 0x7FFFu + ((u >> 16) & 1u)) >> 16);
}
__device__ __forceinline__ float bfup(unsigned short u) {
    return __uint_as_float(((unsigned int)u) << 16);
}
// unpack low/high bf16 of a packed dword
__device__ __forceinline__ float blo(unsigned int v) { return __uint_as_float(v << 16); }
__device__ __forceinline__ float bhi(unsigned int v) { return __uint_as_float(v & 0xFFFF0000u); }

// ---------------- pass 1a: bucket histogram + BN-input stats + graph boundaries ---------
__global__ __launch_bounds__(256) void k_p1hist(const int* __restrict__ ei,
                                                const int* __restrict__ batch,
                                                const float* __restrict__ X,
                                                int* __restrict__ bh,
                                                int* __restrict__ start,
                                                float* __restrict__ gs400,
                                                float* __restrict__ gq400) {
    int t = threadIdx.x;
    if (blockIdx.x < P1B) {
        __shared__ int hist[NB];
        for (int b = t; b < NB; b += 256) hist[b] = 0;
        __syncthreads();
        int e0 = blockIdx.x * P1E;
        #pragma unroll 4
        for (int e = e0 + t; e < e0 + P1E; e += 256)
            atomicAdd(&hist[ei[N_EDGES + e] >> 8], 1);
        __syncthreads();
        for (int b = t; b < NB; b += 256) bh[b * P1B + blockIdx.x] = hist[b];
    } else if (blockIdx.x < P1B + SB) {
        int grp = blockIdx.x - P1B;
        int j4 = (t & 15) * 4;     // 4-col group
        int rg = t >> 4;           // 16 row-groups
        int base = grp * 250;
        float s0 = 0.f, s1 = 0.f, s2 = 0.f, s3 = 0.f;
        float q0 = 0.f, q1 = 0.f, q2 = 0.f, q3 = 0.f;
        for (int i = base + rg; i < base + 250; i += 16) {
            float4 v = *(const float4*)&X[(size_t)i * DIM + j4];
            s0 += v.x; s1 += v.y; s2 += v.z; s3 += v.w;
            q0 += v.x * v.x; q1 += v.y * v.y; q2 += v.z * v.z; q3 += v.w * v.w;
        }
        __shared__ float ls[16 * 64], ls2[16 * 64];
        ls[rg * 64 + j4 + 0] = s0; ls[rg * 64 + j4 + 1] = s1;
        ls[rg * 64 + j4 + 2] = s2; ls[rg * 64 + j4 + 3] = s3;
        ls2[rg * 64 + j4 + 0] = q0; ls2[rg * 64 + j4 + 1] = q1;
        ls2[rg * 64 + j4 + 2] = q2; ls2[rg * 64 + j4 + 3] = q3;
        __syncthreads();
        if (t < 64) {
            float s = 0.f, q = 0.f;
            #pragma unroll
            for (int r = 0; r < 16; r++) { s += ls[r * 64 + t]; q += ls2[r * 64 + t]; }
            gs400[grp * DIM + t] = s;
            gq400[grp * DIM + t] = q;
        }
    } else {
        int i = (blockIdx.x - P1B - SB) * 256 + t;
        if (i < N_NODES) {
            int cur = batch[i];
            if (i == 0) { for (int q = 0; q <= cur; q++) start[q] = 0; }
            else {
                int prev = batch[i - 1];
                for (int q = prev + 1; q <= cur; q++) start[q] = i;
            }
            if (i == N_NODES - 1)
                for (int q = cur + 1; q <= N_GRAPHS; q++) start[q] = N_NODES;
        }
    }
}

// ---------------- scan of bh[NB*1024]  (+ block NB folds input BN, writes Wsc) ---------
// R20: 1024-thread scan blocks -- one bucket row (1024 entries) per block.
__global__ __launch_bounds__(1024) void k_scan1(const int* __restrict__ bh,
                                                int* __restrict__ iscan,
                                                int* __restrict__ bsum,
                                                const float* __restrict__ gs400,
                                                const float* __restrict__ gq400,
                                                const float* __restrict__ bng,
                                                const float* __restrict__ bnb,
                                                const float* __restrict__ W1,
                                                float* __restrict__ Wsc,
                                                float* __restrict__ cshift,
                                                float* __restrict__ gsum32) {
    int t = threadIdx.x;
    if (blockIdx.x == NB) {
        __shared__ float red[256], red2[256];
        __shared__ float ssc[64], shl[64];
        if (t < 256) {
            int j = t & 63, rg = t >> 6;
            float ms = 0.f, m2 = 0.f;
            for (int k2 = rg; k2 < SB; k2 += 4) {
                ms += gs400[k2 * DIM + j];
                m2 += gq400[k2 * DIM + j];
            }
            red[t] = ms; red2[t] = m2;
        }
        __syncthreads();
        if (t < 64) {
            float ms = red[t] + red[64 + t] + red[128 + t] + red[192 + t];
            float m2 = red2[t] + red2[64 + t] + red2[128 + t] + red2[192 + t];
            float mean = ms * (1.0f / N_NODES);
            float var  = m2 * (1.0f / N_NODES) - mean * mean;
            float inv  = 1.0f / sqrtf(var + BN_EPS);
            float sc   = bng[t] * inv;
            ssc[t] = sc;
            shl[t] = bnb[t] - mean * sc;
        }
        __syncthreads();
        if (t < 64) {
            float s = 0.f;
            for (int k2 = 0; k2 < DIM; k2++) s += shl[k2] * W1[k2 * DIM + t];
            cshift[t] = s;
        }
        for (int z = t; z < 4096; z += 1024) Wsc[z] = W1[z] * ssc[z >> 6];
        for (int z = t; z < 2 * NSLOT * DIM; z += 1024) gsum32[z] = 0.f;
        return;
    }
    __shared__ int ls[1024];
    int i = blockIdx.x * 1024 + t;
    int v = bh[i];
    ls[t] = v;
    __syncthreads();
    for (int off = 1; off < 1024; off <<= 1) {
        int tv = (t >= off) ? ls[t - off] : 0;
        __syncthreads();
        ls[t] += tv;
        __syncthreads();
    }
    iscan[i] = ls[t];
    if (t == 1023) bsum[blockIdx.x] = ls[1023];
}

// ---------------- pass 1b: scatter packed {src<<8|dstlow} into bucket-major tmp ---------
// R20: 1024 blocks (4/CU) -- TLP now hides the scatter-store + LDS-atomic latency.
__global__ __launch_bounds__(256) void k_p1scat(const int* __restrict__ ei,
                                                const int* __restrict__ bh,
                                                const int* __restrict__ iscan,
                                                const int* __restrict__ bsum,
                                                int* __restrict__ tmp) {
    __shared__ int cur[NB];
    __shared__ int s0[256], s1[256];
    int t = threadIdx.x, blk = blockIdx.x;
    int v0 = bsum[t];
    int v1 = (t < NB - 256) ? bsum[256 + t] : 0;
    s0[t] = v0; s1[t] = v1;
    __syncthreads();
    for (int off = 1; off < 256; off <<= 1) {
        int a0 = (t >= off) ? s0[t - off] : 0;
        int a1 = (t >= off) ? s1[t - off] : 0;
        __syncthreads();
        s0[t] += a0; s1[t] += a1;
        __syncthreads();
    }
    int carry = s0[255];
    {
        int i = t * P1B + blk;
        cur[t] = (s0[t] - v0) + iscan[i] - bh[i];          // boff[b]=excl prefix
    }
    if (t < NB - 256) {
        int b = 256 + t;
        int i = b * P1B + blk;
        cur[b] = (carry + s1[t] - v1) + iscan[i] - bh[i];
    }
    __syncthreads();
    int e0 = blk * P1E;
    for (int e = e0 + t; e < e0 + P1E; e += 256) {
        int r = ei[e], c = ei[N_EDGES + e];
        int pos = atomicAdd(&cur[c >> 8], 1);
        tmp[pos] = (r << 8) | (c & 255);
    }
}

// ---------------- pass 2 (fused): hist -> rowstart/dinv/winnode -> scatter --------------
__global__ __launch_bounds__(256) void k_p2(const int* __restrict__ tmp,
                                            const int* __restrict__ bsum,
                                            int* __restrict__ rowstart,
                                            float* __restrict__ dinv,
                                            int* __restrict__ winnode,
                                            float* __restrict__ C,
                                            int* __restrict__ csr) {
    int b = blockIdx.x, t = threadIdx.x;
    __shared__ int red[256];
    int part = 0;
    for (int k2 = t; k2 < b; k2 += 256) part += bsum[k2];
    red[t] = part;
    __syncthreads();
    for (int off = 128; off; off >>= 1) {
        if (t < off) red[t] += red[t + off];
        __syncthreads();
    }
    int bstart = red[0];
    int bend = bstart + bsum[b];
    __shared__ int cnt[256], scn[256], curs[256];
    cnt[t] = 0;
    __syncthreads();
    for (int e = bstart + t; e < bend; e += 256)
        atomicAdd(&cnt[tmp[e] & 255], 1);
    __syncthreads();
    scn[t] = cnt[t];
    __syncthreads();
    for (int off = 1; off < 256; off <<= 1) {
        int v = (t >= off) ? scn[t - off] : 0;
        __syncthreads();
        scn[t] += v;
        __syncthreads();
    }
    int node = b * 256 + t;
    int deg = cnt[t];
    int rs = bstart + scn[t] - deg;
    bool span = false;
    if (node <= N_NODES) rowstart[node] = rs;
    if (node == N_NODES) rowstart[node + 1] = rs;   // sentinel for per-lane preload
    if (node < N_NODES) {
        dinv[node] = 1.0f / sqrtf((float)(deg + 1));
        int re = rs + deg;
        for (int w = (rs + WIN - 1) / WIN; w * WIN < re; ++w) winnode[w] = node;
        span = (deg > 0) && (rs / WIN != (re - 1) / WIN);
    }
    // zero C rows of straddler nodes (wave-cooperative: 64 lanes write one row)
    int lane = t & 63;
    int wbase = b * 256 + (t & ~63);
    unsigned long long m = __ballot(span);
    while (m) {
        int bit = __builtin_ctzll(m);
        m &= m - 1;
        C[(size_t)(wbase + bit) * DIM + lane] = 0.f;
    }
    // within-bucket scatter -> final CSR (tmp segment is L1-hot from the histogram pass)
    curs[t] = rs;
    __syncthreads();
    for (int e = bstart + t; e < bend; e += 256) {
        int rec = tmp[e];
        int pos = atomicAdd(&curs[rec & 255], 1);
        csr[pos] = (int)((unsigned)rec >> 8);
    }
}

// ---------------- BN fold (layer 2): reduce 32 slots -> Wsc/cshift, re-zero slots -------
__global__ void k_bnfold(float* __restrict__ gsum, float* __restrict__ gsumsq,
                         const float* __restrict__ g, const float* __restrict__ b,
                         const float* __restrict__ W,
                         float* __restrict__ Wsc, float* __restrict__ cshift) {
    int j = threadIdx.x;
    float ms = 0.f, m2 = 0.f;
    for (int k = 0; k < NSLOT; k++) {
        ms += gsum[k * DIM + j];   gsum[k * DIM + j] = 0.f;
        m2 += gsumsq[k * DIM + j]; gsumsq[k * DIM + j] = 0.f;
    }
    float mean = ms * (1.0f / N_NODES);
    float var  = m2 * (1.0f / N_NODES) - mean * mean;
    float inv  = 1.0f / sqrtf(var + BN_EPS);
    float sc   = g[j] * inv;
    __shared__ float ssc[64], shl[64];
    ssc[j] = sc;
    shl[j] = b[j] - mean * sc;
    __syncthreads();
    float s = 0.f;
    for (int k = 0; k < DIM; k++) s += shl[k] * W[k * DIM + j];
    cshift[j] = s;
    for (int z = j; z < 4096; z += 64) Wsc[z] = W[z] * ssc[z >> 6];
}

// ---------------- GEMM (fp32 A): T' = (X@Wsc + cshift)*dinv[row], bf16 ------------------
// W via scalar loads (wave-uniform addr); A-stage loads vectorized to float4.
__global__ __launch_bounds__(256) void k_gemm_f32(const float* __restrict__ X,
                                                  const float* __restrict__ Wsc,
                                                  const float* __restrict__ cshift,
                                                  const float* __restrict__ dinv,
                                                  unsigned short* __restrict__ T) {
    __shared__ float Al[64 * 65];
    int row0 = blockIdx.x * 64;
    for (int t4 = threadIdx.x; t4 < 1024; t4 += 256) {
        int r = t4 >> 4, k4 = (t4 & 15) * 4;
        int i = row0 + r;
        float4 v = make_float4(0.f, 0.f, 0.f, 0.f);
        if (i < N_NODES) v = *(const float4*)&X[(size_t)i * DIM + k4];
        float* al = &Al[r * 65 + k4];
        al[0] = v.x; al[1] = v.y; al[2] = v.z; al[3] = v.w;
    }
    __syncthreads();
    int r = threadIdx.x & 63;
    int qu = __builtin_amdgcn_readfirstlane(threadIdx.x >> 6);
    float acc[16];
    #pragma unroll
    for (int jj = 0; jj < 16; jj++) acc[jj] = cshift[qu * 16 + jj];
    #pragma unroll 4
    for (int k = 0; k < 64; k++) {
        float a = Al[r * 65 + k];
        const float4* wv = (const float4*)(Wsc + (k << 6) + (qu << 4));
        float4 w0 = wv[0], w1 = wv[1], w2 = wv[2], w3 = wv[3];
        acc[0]  += a * w0.x; acc[1]  += a * w0.y; acc[2]  += a * w0.z; acc[3]  += a * w0.w;
        acc[4]  += a * w1.x; acc[5]  += a * w1.y; acc[6]  += a * w1.z; acc[7]  += a * w1.w;
        acc[8]  += a * w2.x; acc[9]  += a * w2.y; acc[10] += a * w2.z; acc[11] += a * w2.w;
        acc[12] += a * w3.x; acc[13] += a * w3.y; acc[14] += a * w3.z; acc[15] += a * w3.w;
    }
    int i = row0 + r;
    if (i < N_NODES) {
        float dv = dinv[i];
        unsigned int pk[8];
        #pragma unroll
        for (int jj = 0; jj < 8; jj++)
            pk[jj] = bf16_rtn2(acc[2 * jj] * dv, acc[2 * jj + 1] * dv);
        uint4* outv = (uint4*)&T[(size_t)i * DIM + qu * 16];
        outv[0] = make_uint4(pk[0], pk[1], pk[2], pk[3]);
        outv[1] = make_uint4(pk[4], pk[5], pk[6], pk[7]);
    }
}

// ---------------- GEMM (bf16 A): T' = (H@Wsc + cshift)*dinv[row], bf16 ------------------
// Blocks < N_GRAPHS also zero their pool row. A-stage loads vectorized (8 bf16).
__global__ __launch_bounds__(256) void k_gemm_b16(const unsigned short* __restrict__ X,
                                                  const float* __restrict__ Wsc,
                                                  const float* __restrict__ cshift,
                                                  const float* __restrict__ dinv,
                                                  unsigned short* __restrict__ T,
                                                  float* __restrict__ pool) {
    if (blockIdx.x < N_GRAPHS && threadIdx.x < 64)
        pool[(size_t)blockIdx.x * DIM + threadIdx.x] = 0.f;
    __shared__ float Al[64 * 65];
    int row0 = blockIdx.x * 64;
    for (int t8 = threadIdx.x; t8 < 512; t8 += 256) {
        int r = t8 >> 3, k8 = (t8 & 7) * 8;
        int i = row0 + r;
        uint4 v = make_uint4(0u, 0u, 0u, 0u);
        if (i < N_NODES) v = *(const uint4*)&X[(size_t)i * DIM + k8];
        float* al = &Al[r * 65 + k8];
        al[0] = blo(v.x); al[1] = bhi(v.x);
        al[2] = blo(v.y); al[3] = bhi(v.y);
        al[4] = blo(v.z); al[5] = bhi(v.z);
        al[6] = blo(v.w); al[7] = bhi(v.w);
    }
    __syncthreads();
    int r = threadIdx.x & 63;
    int qu = __builtin_amdgcn_readfirstlane(threadIdx.x >> 6);
    float acc[16];
    #pragma unroll
    for (int jj = 0; jj < 16; jj++) acc[jj] = cshift[qu * 16 + jj];
    #pragma unroll 4
    for (int k = 0; k < 64; k++) {
        float a = Al[r * 65 + k];
        const float4* wv = (const float4*)(Wsc + (k << 6) + (qu << 4));
        float4 w0 = wv[0], w1 = wv[1], w2 = wv[2], w3 = wv[3];
        acc[0]  += a * w0.x; acc[1]  += a * w0.y; acc[2]  += a * w0.z; acc[3]  += a * w0.w;
        acc[4]  += a * w1.x; acc[5]  += a * w1.y; acc[6]  += a * w1.z; acc[7]  += a * w1.w;
        acc[8]  += a * w2.x; acc[9]  += a * w2.y; acc[10] += a * w2.z; acc[11] += a * w2.w;
        acc[12] += a * w3.x; acc[13] += a * w3.y; acc[14] += a * w3.z; acc[15] += a * w3.w;
    }
    int i = row0 + r;
    if (i < N_NODES) {
        float dv = dinv[i];
        unsigned int pk[8];
        #pragma unroll
        for (int jj = 0; jj < 8; jj++)
            pk[jj] = bf16_rtn2(acc[2 * jj] * dv, acc[2 * jj + 1] * dv);
        uint4* outv = (uint4*)&T[(size_t)i * DIM + qu * 16];
        outv[0] = make_uint4(pk[0], pk[1], pk[2], pk[3]);
        outv[1] = make_uint4(pk[4], pk[5], pk[6], pk[7]);
    }
}

// ================= gather kernels (R15, unchanged: 64-lane atomics, WIN=128) ============
#define SWZ(V, S) __builtin_amdgcn_ds_swizzle((V), (((S) << 5) | 0x10))

#define ISSUE(SRCV, TVV, CV, S0) do {                                 \
    SRCV[0] = SWZ(CV, (S0) + 0); SRCV[1] = SWZ(CV, (S0) + 1);         \
    SRCV[2] = SWZ(CV, (S0) + 2); SRCV[3] = SWZ(CV, (S0) + 3);         \
    TVV[0] = T2[(unsigned)SRCV[0] * 16u + cc];                        \
    TVV[1] = T2[(unsigned)SRCV[1] * 16u + cc];                        \
    TVV[2] = T2[(unsigned)SRCV[2] * 16u + cc];                        \
    TVV[3] = T2[(unsigned)SRCV[3] * 16u + cc];                        \
} while (0)

#define STEP(TVV, U, B, FL) do {                                      \
    const int ebs = e0 + 16 * (B) + 4 * (U);                          \
    uint2 tvv = TVV[U];                                               \
    float a0 = blo(tvv.x), a1 = bhi(tvv.x);                           \
    float a2 = blo(tvv.y), a3 = bhi(tvv.y);                           \
    if (re > ebs + 3) {                                               \
        acc0 += a0; acc1 += a1; acc2 += a2; acc3 += a3;               \
    } else {                                                          \
        int lo = ebs;                                                 \
        while (re <= ebs + 3) {                                       \
            int eg = ebs + gg;                                        \
            if (eg >= lo && eg < re) {                                \
                acc0 += a0; acc1 += a1; acc2 += a2; acc3 += a3;       \
            }                                                         \
            lo = re;                                                  \
            FL();                                                     \
        }                                                             \
        if (ebs + gg >= lo) {                                         \
            acc0 += a0; acc1 += a1; acc2 += a2; acc3 += a3;           \
        }                                                             \
    }                                                                 \
} while (0)

#define CONSUME(TVV, B, FL) do {                                      \
    STEP(TVV, 0, B, FL); STEP(TVV, 1, B, FL);                         \
    STEP(TVV, 2, B, FL); STEP(TVV, 3, B, FL);                         \
} while (0)

#define COMB4()                                                       \
    float t0 = acc0 + __shfl_xor(acc0, 16); t0 += __shfl_xor(t0, 32); \
    float t1 = acc1 + __shfl_xor(acc1, 16); t1 += __shfl_xor(t1, 32); \
    float t2 = acc2 + __shfl_xor(acc2, 16); t2 += __shfl_xor(t2, 32); \
    float t3 = acc3 + __shfl_xor(acc3, 16); t3 += __shfl_xor(t3, 32);

#define REDIST64(OUT, V0, V1, V2, V3)                                 \
    float _r0 = __shfl((V0), lane >> 2);                              \
    float _r1 = __shfl((V1), lane >> 2);                              \
    float _r2 = __shfl((V2), lane >> 2);                              \
    float _r3 = __shfl((V3), lane >> 2);                              \
    float OUT = (lane & 2) ? ((lane & 1) ? _r3 : _r2)                 \
                           : ((lane & 1) ? _r1 : _r0);

#define ADVANCE() do {                                                \
    acc0 = acc1 = acc2 = acc3 = 0.f;                                  \
    ++i; ++k;                                                         \
    if (k < 64) re = __builtin_amdgcn_readlane(rsv, k);               \
    else        re = __builtin_amdgcn_readfirstlane(rowstart[i + 1]); \
    tsv = T2[(unsigned)i * 16u + cc];                                 \
} while (0)

#define FLUSH1() do {                                                 \
    COMB4();                                                          \
    if (part) {                                                       \
        REDIST64(cv, t0, t1, t2, t3);                                 \
        atomicAdd(&C[(size_t)i * DIM + lane], cv);                    \
        part = false;                                                 \
    } else {                                                          \
        int cnt = i - i0;                                             \
        float di;                                                     \
        if (cnt < 64)                                                 \
            di = __int_as_float(                                      \
                __builtin_amdgcn_readlane(__float_as_int(dv), cnt));  \
        else di = dinv[i];                                            \
        float h0 = fmaxf((t0 + blo(tsv.x)) * di + bb.x, 0.f);         \
        float h1 = fmaxf((t1 + bhi(tsv.x)) * di + bb.y, 0.f);         \
        float h2 = fmaxf((t2 + blo(tsv.y)) * di + bb.z, 0.f);         \
        float h3 = fmaxf((t3 + bhi(tsv.y)) * di + bb.w, 0.f);         \
        if (lane < 16)                                                \
            ((uint2*)H)[(unsigned)i * 16u + cc] =                     \
                make_uint2(bf16_rtn2(h0, h1), bf16_rtn2(h2, h3));     \
        s0 += h0; s1 += h1; s2 += h2; s3 += h3;                       \
        q0 += h0 * h0; q1 += h1 * h1; q2 += h2 * h2; q3 += h3 * h3;   \
    }                                                                 \
    ADVANCE();                                                        \
} while (0)

__global__ __launch_bounds__(256) void k_gather1(const unsigned short* __restrict__ T,
                                                 const float* __restrict__ dinv,
                                                 const int* __restrict__ rowstart,
                                                 const int* __restrict__ winnode,
                                                 const int* __restrict__ csr,
                                                 const float* __restrict__ bias,
                                                 float* __restrict__ C,
                                                 unsigned short* __restrict__ H,
                                                 float* __restrict__ gsum,
                                                 float* __restrict__ gsumsq) {
    const int lane = threadIdx.x & 63;
    const int gg = lane >> 4;          // edge sub-slot 0..3
    const int cc = lane & 15;          // uint2 index: cols 4cc..4cc+3
    const int w = blockIdx.x * 4 + (threadIdx.x >> 6);
    const int e0 = w * WIN;
    const int eend = e0 + WIN;
    const uint2* T2 = (const uint2*)T;

    int csrv0 = csr[e0 + 4 * cc + gg];                    // permuted window csr (1st 64)
    int csrv1 = csr[e0 + 64 + 4 * cc + gg];               // (2nd 64)
    int i0 = __builtin_amdgcn_readfirstlane(winnode[w]);
    int rsv = rowstart[min(i0 + lane, N_NODES + 1)];      // per-lane rowstart cache
    float dv = dinv[min(i0 + lane, N_NODES - 1)];         // per-lane dinv cache
    uint2 tsv = T2[(unsigned)i0 * 16u + cc];              // self-row prefetch
    const float4 bb = ((const float4*)bias)[cc];

    int i = i0, k = 1;
    int re = __builtin_amdgcn_readlane(rsv, 1);
    bool part = __builtin_amdgcn_readlane(rsv, 0) < e0;
    float acc0 = 0.f, acc1 = 0.f, acc2 = 0.f, acc3 = 0.f;
    float s0 = 0.f, s1 = 0.f, s2 = 0.f, s3 = 0.f;
    float q0 = 0.f, q1 = 0.f, q2 = 0.f, q3 = 0.f;

    int srcA[4], srcB[4], srcC[4], srcD[4];
    uint2 tva[4], tvb[4], tvc[4], tvd[4];
    ISSUE(srcA, tva, csrv0, 0);
    ISSUE(srcB, tvb, csrv0, 4);
    ISSUE(srcC, tvc, csrv0, 8);
    ISSUE(srcD, tvd, csrv0, 12);
    CONSUME(tva, 0, FLUSH1);  ISSUE(srcA, tva, csrv1, 0);
    CONSUME(tvb, 1, FLUSH1);  ISSUE(srcB, tvb, csrv1, 4);
    CONSUME(tvc, 2, FLUSH1);  ISSUE(srcC, tvc, csrv1, 8);
    CONSUME(tvd, 3, FLUSH1);  ISSUE(srcD, tvd, csrv1, 12);
    CONSUME(tva, 4, FLUSH1);
    CONSUME(tvb, 5, FLUSH1);
    CONSUME(tvc, 6, FLUSH1);
    CONSUME(tvd, 7, FLUSH1);

    if (part || re > eend) {
        COMB4();
        REDIST64(cv, t0, t1, t2, t3);
        atomicAdd(&C[(size_t)i * DIM + lane], cv);
    } else {
        FLUSH1();
    }

    __shared__ float shs[4][64], shq[4][64];
    int wv = threadIdx.x >> 6;
    if (lane < 16) {
        shs[wv][4 * cc + 0] = s0; shs[wv][4 * cc + 1] = s1;
        shs[wv][4 * cc + 2] = s2; shs[wv][4 * cc + 3] = s3;
        shq[wv][4 * cc + 0] = q0; shq[wv][4 * cc + 1] = q1;
        shq[wv][4 * cc + 2] = q2; shq[wv][4 * cc + 3] = q3;
    }
    __syncthreads();
    if (threadIdx.x < 64) {
        int j = threadIdx.x;
        float vs = shs[0][j] + shs[1][j] + shs[2][j] + shs[3][j];
        float vq = shq[0][j] + shq[1][j] + shq[2][j] + shq[3][j];
        int slot = (blockIdx.x & (NSLOT - 1)) * DIM;
        atomicAdd(&gsum[slot + j], vs);
        atomicAdd(&gsumsq[slot + j], vq);
    }
}

#define FLUSH2() do {                                                 \
    COMB4();                                                          \
    if (part) {                                                       \
        REDIST64(cv, t0, t1, t2, t3);                                 \
        atomicAdd(&C[(size_t)i * DIM + lane], cv);                    \
        part = false;                                                 \
    } else {                                                          \
        int cnt = i - i0;                                             \
        float di;                                                     \
        int gi;                                                       \
        if (cnt < 64) {                                               \
            di = __int_as_float(                                      \
                __builtin_amdgcn_readlane(__float_as_int(dv), cnt));  \
            gi = __builtin_amdgcn_readlane(bv, cnt);                  \
        } else { di = dinv[i]; gi = batch[i]; }                       \
        float h0 = fmaxf((t0 + blo(tsv.x)) * di + bb.x, 0.f);         \
        float h1 = fmaxf((t1 + bhi(tsv.x)) * di + bb.y, 0.f);         \
        float h2 = fmaxf((t2 + blo(tsv.y)) * di + bb.z, 0.f);         \
        float h3 = fmaxf((t3 + bhi(tsv.y)) * di + bb.w, 0.f);         \
        s0 += h0; s1 += h1; s2 += h2; s3 += h3;                       \
        q0 += h0 * h0; q1 += h1 * h1; q2 += h2 * h2; q3 += h3 * h3;   \
        if (gi != cur_g) {                                            \
            if (cur_g >= 0) {                                         \
                REDIST64(pv, ps0, ps1, ps2, ps3);                     \
                atomicAdd(&pool[(size_t)cur_g * DIM + lane], pv);     \
            }                                                         \
            ps0 = ps1 = ps2 = ps3 = 0.f;                              \
            cur_g = gi;                                               \
        }                                                             \
        ps0 += h0; ps1 += h1; ps2 += h2; ps3 += h3;                   \
    }                                                                 \
    ADVANCE();                                                        \
} while (0)

__global__ __launch_bounds__(256) void k_gather2(const unsigned short* __restrict__ T,
                                                 const float* __restrict__ dinv,
                                                 const int* __restrict__ rowstart,
                                                 const int* __restrict__ winnode,
                                                 const int* __restrict__ csr,
                                                 const float* __restrict__ bias,
                                                 const int* __restrict__ batch,
                                                 float* __restrict__ C,
                                                 float* __restrict__ pool,
                                                 float* __restrict__ gsum,
                                                 float* __restrict__ gsumsq) {
    const int lane = threadIdx.x & 63;
    const int gg = lane >> 4;
    const int cc = lane & 15;
    const int w = blockIdx.x * 4 + (threadIdx.x >> 6);
    const int e0 = w * WIN;
    const int eend = e0 + WIN;
    const uint2* T2 = (const uint2*)T;

    int csrv0 = csr[e0 + 4 * cc + gg];
    int csrv1 = csr[e0 + 64 + 4 * cc + gg];
    int i0 = __builtin_amdgcn_readfirstlane(winnode[w]);
    int rsv = rowstart[min(i0 + lane, N_NODES + 1)];
    float dv = dinv[min(i0 + lane, N_NODES - 1)];
    int bv = batch[min(i0 + lane, N_NODES - 1)];
    uint2 tsv = T2[(unsigned)i0 * 16u + cc];
    const float4 bb = ((const float4*)bias)[cc];

    int i = i0, k = 1;
    int re = __builtin_amdgcn_readlane(rsv, 1);
    bool part = __builtin_amdgcn_readlane(rsv, 0) < e0;
    float acc0 = 0.f, acc1 = 0.f, acc2 = 0.f, acc3 = 0.f;
    float s0 = 0.f, s1 = 0.f, s2 = 0.f, s3 = 0.f;
    float q0 = 0.f, q1 = 0.f, q2 = 0.f, q3 = 0.f;
    float ps0 = 0.f, ps1 = 0.f, ps2 = 0.f, ps3 = 0.f;
    int cur_g = -1;

    int srcA[4], srcB[4], srcC[4], srcD[4];
    uint2 tva[4], tvb[4], tvc[4], tvd[4];
    ISSUE(srcA, tva, csrv0, 0);
    ISSUE(srcB, tvb, csrv0, 4);
    ISSUE(srcC, tvc, csrv0, 8);
    ISSUE(srcD, tvd, csrv0, 12);
    CONSUME(tva, 0, FLUSH2);  ISSUE(srcA, tva, csrv1, 0);
    CONSUME(tvb, 1, FLUSH2);  ISSUE(srcB, tvb, csrv1, 4);
    CONSUME(tvc, 2, FLUSH2);  ISSUE(srcC, tvc, csrv1, 8);
    CONSUME(tvd, 3, FLUSH2);  ISSUE(srcD, tvd, csrv1, 12);
    CONSUME(tva, 4, FLUSH2);
    CONSUME(tvb, 5, FLUSH2);
    CONSUME(tvc, 6, FLUSH2);
    CONSUME(tvd, 7, FLUSH2);

    if (part || re > eend) {
        COMB4();
        REDIST64(cv, t0, t1, t2, t3);
        atomicAdd(&C[(size_t)i * DIM + lane], cv);
    } else {
        FLUSH2();
    }
    if (cur_g >= 0) {
        REDIST64(pv, ps0, ps1, ps2, ps3);
        atomicAdd(&pool[(size_t)cur_g * DIM + lane], pv);
    }

    __shared__ float shs[4][64], shq[4][64];
    int wv = threadIdx.x >> 6;
    if (lane < 16) {
        shs[wv][4 * cc + 0] = s0; shs[wv][4 * cc + 1] = s1;
        shs[wv][4 * cc + 2] = s2; shs[wv][4 * cc + 3] = s3;
        shq[wv][4 * cc + 0] = q0; shq[wv][4 * cc + 1] = q1;
        shq[wv][4 * cc + 2] = q2; shq[wv][4 * cc + 3] = q3;
    }
    __syncthreads();
    if (threadIdx.x < 64) {
        int j = threadIdx.x;
        float vs = shs[0][j] + shs[1][j] + shs[2][j] + shs[3][j];
        float vq = shq[0][j] + shq[1][j] + shq[2][j] + shq[3][j];
        int slot = (blockIdx.x & (NSLOT - 1)) * DIM;
        atomicAdd(&gsum[slot + j], vs);
        atomicAdd(&gsumsq[slot + j], vq);
    }
}

// ---------------- straddler + boundary-deg0 finish, layer 1 (-> H + stats) --------------
__global__ __launch_bounds__(256) void k_strad1(float* __restrict__ C,
                                                const unsigned short* __restrict__ T,
                                                const float* __restrict__ dinv,
                                                const int* __restrict__ rowstart,
                                                const int* __restrict__ winnode,
                                                const float* __restrict__ bias,
                                                unsigned short* __restrict__ H,
                                                float* __restrict__ gsum,
                                                float* __restrict__ gsumsq) {
    int lane = threadIdx.x & 63;
    int wv = threadIdx.x >> 6;
    float bb = bias[lane];
    float s = 0.f, s2 = 0.f;
    __shared__ int anyw;
    if (threadIdx.x == 0) anyw = 0;
    __syncthreads();
    if (blockIdx.x < NWIN / 4) {
        int w = blockIdx.x * 4 + wv;
        int n = winnode[w];
        int rs = rowstart[n];
        if (w == rs / WIN + 1) {
            float di = dinv[n];
            float c = C[(size_t)n * DIM + lane];
            C[(size_t)n * DIM + lane] = 0.f;        // re-zero for layer 2
            float h = fmaxf((c + bfup(T[(size_t)n * DIM + lane])) * di + bb, 0.f);
            H[(size_t)n * DIM + lane] = bf16r(h);
            s += h; s2 += h * h;
            anyw = 1;
        }
    } else {
        int base = (blockIdx.x - NWIN / 4) * 256 + wv * 64;
        int nb = base + lane;
        int d0 = 0;
        if (nb < N_NODES)
            d0 = (rowstart[nb + 1] == rowstart[nb]) && ((rowstart[nb] & (WIN - 1)) == 0);
        unsigned long long m = __ballot(d0);
        while (m) {
            int b = __builtin_ctzll(m);
            m &= m - 1;
            int n = base + b;
            float di = dinv[n];
            float h = fmaxf(bfup(T[(size_t)n * DIM + lane]) * di + bb, 0.f);
            H[(size_t)n * DIM + lane] = bf16r(h);
            s += h; s2 += h * h;
            anyw = 1;
        }
    }
    __shared__ float ls[256], ls2[256];
    ls[threadIdx.x] = s; ls2[threadIdx.x] = s2;
    __syncthreads();
    if (anyw && threadIdx.x < 64) {
        int j = threadIdx.x;
        int slot = (blockIdx.x & (NSLOT - 1)) * DIM;
        atomicAdd(&gsum[slot + j],   ls[j] + ls[64 + j] + ls[128 + j] + ls[192 + j]);
        atomicAdd(&gsumsq[slot + j], ls2[j] + ls2[64 + j] + ls2[128 + j] + ls2[192 + j]);
    }
}

// ---------------- straddler + boundary-deg0 finish, layer 2 (-> pool + stats) -----------
__global__ __launch_bounds__(256) void k_strad2(const float* __restrict__ C,
                                                const unsigned short* __restrict__ T,
                                                const float* __restrict__ dinv,
                                                const int* __restrict__ rowstart,
                                                const int* __restrict__ winnode,
                                                const float* __restrict__ bias,
                                                const int* __restrict__ batch,
                                                float* __restrict__ pool,
                                                float* __restrict__ gsum,
                                                float* __restrict__ gsumsq) {
    int lane = threadIdx.x & 63;
    int wv = threadIdx.x >> 6;
    float bb = bias[lane];
    float s = 0.f, s2 = 0.f;
    __shared__ int anyw;
    if (threadIdx.x == 0) anyw = 0;
    __syncthreads();
    if (blockIdx.x < NWIN / 4) {
        int w = blockIdx.x * 4 + wv;
        int n = winnode[w];
        int rs = rowstart[n];
        if (w == rs / WIN + 1) {
            float di = dinv[n];
            float h = fmaxf((C[(size_t)n * DIM + lane]
                             + bfup(T[(size_t)n * DIM + lane])) * di + bb, 0.f);
            s += h; s2 += h * h;
            atomicAdd(&pool[(size_t)batch[n] * DIM + lane], h);
            anyw = 1;
        }
    } else {
        int base = (blockIdx.x - NWIN / 4) * 256 + wv * 64;
        int nb = base + lane;
        int d0 = 0;
        if (nb < N_NODES)
            d0 = (rowstart[nb + 1] == rowstart[nb]) && ((rowstart[nb] & (WIN - 1)) == 0);
        unsigned long long m = __ballot(d0);
        while (m) {
            int b = __builtin_ctzll(m);
            m &= m - 1;
            int n = base + b;
            float di = dinv[n];
            float h = fmaxf(bfup(T[(size_t)n * DIM + lane]) * di + bb, 0.f);
            s += h; s2 += h * h;
            atomicAdd(&pool[(size_t)batch[n] * DIM + lane], h);
            anyw = 1;
        }
    }
    __shared__ float ls[256], ls2[256];
    ls[threadIdx.x] = s; ls2[threadIdx.x] = s2;
    __syncthreads();
    if (anyw && threadIdx.x < 64) {
        int j = threadIdx.x;
        int slot = (blockIdx.x & (NSLOT - 1)) * DIM;
        atomicAdd(&gsum[slot + j],   ls[j] + ls[64 + j] + ls[128 + j] + ls[192 + j]);
        atomicAdd(&gsumsq[slot + j], ls2[j] + ls2[64 + j] + ls2[128 + j] + ls2[192 + j]);
    }
}

// ---------------- final (fused BN2 fold): per-block scale/shift from 32 slots -----------
__global__ void k_final(const float* __restrict__ pool, const int* __restrict__ start,
                        const float* __restrict__ gsum, const float* __restrict__ gsumsq,
                        const float* __restrict__ g, const float* __restrict__ be,
                        const float* __restrict__ Wout, const float* __restrict__ bout,
                        float* __restrict__ out) {
    int gr = blockIdx.x;
    int l = threadIdx.x;
    float ms = 0.f, m2 = 0.f;
    for (int k = 0; k < NSLOT; k++) { ms += gsum[k * DIM + l]; m2 += gsumsq[k * DIM + l]; }
    float mean = ms * (1.0f / N_NODES);
    float var  = m2 * (1.0f / N_NODES) - mean * mean;
    float inv  = 1.0f / sqrtf(var + BN_EPS);
    float sc   = g[l] * inv;
    float sh   = be[l] - mean * sc;
    float c = fmaxf((float)(start[gr + 1] - start[gr]), 1.f);
    float p = (pool[gr * DIM + l] / c) * sc + sh;
    float a0 = p * Wout[l * 2 + 0];
    float a1 = p * Wout[l * 2 + 1];
    #pragma unroll
    for (int off = 32; off; off >>= 1) {
        a0 += __shfl_down(a0, off, 64);
        a1 += __shfl_down(a1, off, 64);
    }
    if (l == 0) {
        out[gr * 2 + 0] = a0 + bout[0];
        out[gr * 2 + 1] = a1 + bout[1];
    }
}

extern "C" void kernel_launch(void* const* d_in, const int* in_sizes, int n_in,
                              void* d_out, int out_size, void* d_ws, size_t ws_size,
                              hipStream_t stream) {
    (void)in_sizes; (void)n_in; (void)out_size; (void)ws_size;
    const float* x       = (const float*)d_in[0];
    const int*   ei      = (const int*)d_in[1];
    const int*   batch   = (const int*)d_in[2];
    const float* bn_in_g = (const float*)d_in[3];
    const float* bn_in_b = (const float*)d_in[4];
    const float* W1      = (const float*)d_in[5];
    const float* b1      = (const float*)d_in[6];
    const float* g1      = (const float*)d_in[7];
    const float* be1     = (const float*)d_in[8];
    const float* W2      = (const float*)d_in[9];
    const float* b2      = (const float*)d_in[10];
    const float* g2      = (const float*)d_in[11];
    const float* be2     = (const float*)d_in[12];
    const float* Wout    = (const float*)d_in[13];
    const float* bout    = (const float*)d_in[14];
    float* out = (float*)d_out;

    // workspace layout; all offsets kept 16B-aligned for float4 global reads
    char* p = (char*)d_ws;
    float* C = (float*)p;                   p += (size_t)N_NODES * DIM * 4;  // 25.6 MB
    unsigned short* H = (unsigned short*)p; p += (size_t)N_NODES * DIM * 2;  // 12.8 MB
    unsigned short* T = (unsigned short*)p; p += (size_t)N_NODES * DIM * 2;  // 12.8 MB
    int* csr = (int*)p;                     p += (size_t)N_EDGES * 4;        // 5.12 MB
    float* dinv = (float*)p;                p += N_NODES * 4;
    int* bh = (int*)p;                      p += (size_t)NB * P1B * 4;       // 1.6 MB
    int* iscan = (int*)p;                   p += (size_t)NB * P1B * 4;       // 1.6 MB
    int* rowstart = (int*)p;                p += (N_NODES + 4) * 4;          // 16B-pad
    int* winnode = (int*)p;                 p += NWIN * 4;
    int* bsum = (int*)p;                    p += NB * 4;
    int* start = (int*)p;                   p += (N_GRAPHS + 4) * 4;         // 16B-pad
    float* gsum32 = (float*)p;              p += NSLOT * DIM * 4;            // atomic slots
    float* gsumsq32 = (float*)p;            p += NSLOT * DIM * 4;            // (contiguous)
    float* gs400 = (float*)p;               p += (size_t)SB * DIM * 4;       // input stats
    float* gq400 = (float*)p;               p += (size_t)SB * DIM * 4;
    float* Wsc = (float*)p;                 p += 4096 * 4;                   // scaled W
    float* cshift = (float*)p;              p += DIM * 4;
    float* pool = (float*)p;                p += (size_t)N_GRAPHS * DIM * 4;
    int* tmp = (int*)H;   // packed bucket-sort temp aliases H (dead before gather1 writes H)

    // ---- CSR build + BN-input stats + graph boundaries ----
    k_p1hist<<<P1B + SB + 392, 256, 0, stream>>>(ei, batch, x, bh, start, gs400, gq400);
    k_scan1<<<NB + 1, 1024, 0, stream>>>(bh, iscan, bsum, gs400, gq400,
                                         bn_in_g, bn_in_b, W1, Wsc, cshift, gsum32);
    k_p1scat<<<P1B, 256, 0, stream>>>(ei, bh, iscan, bsum, tmp);
    k_p2<<<NB, 256, 0, stream>>>(tmp, bsum, rowstart, dinv, winnode, C, csr);

    // ---- GEMM1 (scalar-W) -> gather1 -> straddle ----
    k_gemm_f32<<<(N_NODES + 63) / 64, 256, 0, stream>>>(x, Wsc, cshift, dinv, T);
    k_gather1<<<NWIN / 4, 256, 0, stream>>>(T, dinv, rowstart, winnode, csr, b1,
                                            C, H, gsum32, gsumsq32);
    k_strad1<<<NWIN / 4 + 392, 256, 0, stream>>>(C, T, dinv, rowstart, winnode, b1,
                                                 H, gsum32, gsumsq32);

    // ---- BN1 fold (writes Wsc for layer 2) -> GEMM2 (+pool zero) -> gather2 -> straddle
    k_bnfold<<<1, 64, 0, stream>>>(gsum32, gsumsq32, g1, be1, W2, Wsc, cshift);
    k_gemm_b16<<<(N_NODES + 63) / 64, 256, 0, stream>>>(H, Wsc, cshift, dinv, T, pool);
    k_gather2<<<NWIN / 4, 256, 0, stream>>>(T, dinv, rowstart, winnode, csr, b2,
                                            batch, C, pool, gsum32, gsumsq32);
    k_strad2<<<NWIN / 4 + 392, 256, 0, stream>>>(C, T, dinv, rowstart, winnode, b2,
                                                 batch, pool, gsum32, gsumsq32);

    // ---- final (BN2 fold fused per-block) ----
    k_final<<<N_GRAPHS, 64, 0, stream>>>(pool, start, gsum32, gsumsq32, g2, be2,
                                         Wout, bout, out);
}

// Round 9
// 298.313 us; speedup vs baseline: 1.1594x; 1.1594x over previous
//
#include <hip/hip_runtime.h>
#include <math.h>

#define N_NODES 100000
#define N_EDGES 1280000
#define DIM 64
#define N_GRAPHS 1000
#define BN_EPS 1e-5f
#define NB 392            // buckets = dst>>8; 392*256 = 100352 >= N_NODES
#define P1B 256           // pass-1 histogram blocks; 256*5000 = 1.28M exactly
#define P1E 5000
#define SB 400            // stats blocks (400*250 = 100k rows, contiguous spans)
#define WIN 128           // edges per gather wave window
#define NWIN (N_EDGES / WIN)   // 10000
#define NSLOT 32          // BN-stat partial slots

// ---- bf16 helpers (top 16 bits of fp32, RTN) ----
__device__ __forceinline__ unsigned int bf16_rtn2(float a, float b) {
    unsigned int ua = __float_as_uint(a);
    unsigned int ub = __float_as_uint(b);
    ua = (ua + 0x7FFFu + ((ua >> 16) & 1u)) >> 16;
    ub = (ub + 0x7FFFu + ((ub >> 16) & 1u)) >> 16;
    return ua | (ub << 16);
}
__device__ __forceinline__ unsigned short bf16r(float a) {
    unsigned int u = __float_as_uint(a);
    return (unsigned short)((u + 0x7FFFu + ((u >> 16) & 1u)) >> 16);
}
__device__ __forceinline__ float bfup(unsigned short u) {
    return __uint_as_float(((unsigned int)u) << 16);
}
// unpack low/high bf16 of a packed dword
__device__ __forceinline__ float blo(unsigned int v) { return __uint_as_float(v << 16); }
__device__ __forceinline__ float bhi(unsigned int v) { return __uint_as_float(v & 0xFFFF0000u); }

// ---------------- pass 1a: bucket histogram + BN-input stats + graph boundaries ---------
// Stats branch reads X via float4 (4 cols x 16 row-groups per thread).
__global__ __launch_bounds__(256) void k_p1hist(const int* __restrict__ ei,
                                                const int* __restrict__ batch,
                                                const float* __restrict__ X,
                                                int* __restrict__ bh,
                                                int* __restrict__ start,
                                                float* __restrict__ gs400,
                                                float* __restrict__ gq400) {
    int t = threadIdx.x;
    if (blockIdx.x < P1B) {
        __shared__ int hist[NB];
        for (int b = t; b < NB; b += 256) hist[b] = 0;
        __syncthreads();
        int e0 = blockIdx.x * P1E;
        #pragma unroll 4
        for (int e = e0 + t; e < e0 + P1E; e += 256)
            atomicAdd(&hist[ei[N_EDGES + e] >> 8], 1);
        __syncthreads();
        for (int b = t; b < NB; b += 256) bh[b * P1B + blockIdx.x] = hist[b];
    } else if (blockIdx.x < P1B + SB) {
        int grp = blockIdx.x - P1B;
        int j4 = (t & 15) * 4;     // 4-col group
        int rg = t >> 4;           // 16 row-groups
        int base = grp * 250;
        float s0 = 0.f, s1 = 0.f, s2 = 0.f, s3 = 0.f;
        float q0 = 0.f, q1 = 0.f, q2 = 0.f, q3 = 0.f;
        for (int i = base + rg; i < base + 250; i += 16) {
            float4 v = *(const float4*)&X[(size_t)i * DIM + j4];
            s0 += v.x; s1 += v.y; s2 += v.z; s3 += v.w;
            q0 += v.x * v.x; q1 += v.y * v.y; q2 += v.z * v.z; q3 += v.w * v.w;
        }
        __shared__ float ls[16 * 64], ls2[16 * 64];
        ls[rg * 64 + j4 + 0] = s0; ls[rg * 64 + j4 + 1] = s1;
        ls[rg * 64 + j4 + 2] = s2; ls[rg * 64 + j4 + 3] = s3;
        ls2[rg * 64 + j4 + 0] = q0; ls2[rg * 64 + j4 + 1] = q1;
        ls2[rg * 64 + j4 + 2] = q2; ls2[rg * 64 + j4 + 3] = q3;
        __syncthreads();
        if (t < 64) {
            float s = 0.f, q = 0.f;
            #pragma unroll
            for (int r = 0; r < 16; r++) { s += ls[r * 64 + t]; q += ls2[r * 64 + t]; }
            gs400[grp * DIM + t] = s;
            gq400[grp * DIM + t] = q;
        }
    } else {
        int i = (blockIdx.x - P1B - SB) * 256 + t;
        if (i < N_NODES) {
            int cur = batch[i];
            if (i == 0) { for (int q = 0; q <= cur; q++) start[q] = 0; }
            else {
                int prev = batch[i - 1];
                for (int q = prev + 1; q <= cur; q++) start[q] = i;
            }
            if (i == N_NODES - 1)
                for (int q = cur + 1; q <= N_GRAPHS; q++) start[q] = N_NODES;
        }
    }
}

// ---------------- scan of bh[100352]  (+ block NB folds input BN, writes Wsc) ----------
__global__ __launch_bounds__(256) void k_scan1(const int* __restrict__ bh,
                                               int* __restrict__ iscan,
                                               int* __restrict__ bsum,
                                               const float* __restrict__ gs400,
                                               const float* __restrict__ gq400,
                                               const float* __restrict__ bng,
                                               const float* __restrict__ bnb,
                                               const float* __restrict__ W1,
                                               float* __restrict__ Wsc,
                                               float* __restrict__ cshift,
                                               float* __restrict__ gsum32) {
    int t = threadIdx.x;
    if (blockIdx.x == NB) {
        __shared__ float red[256], red2[256];
        __shared__ float ssc[64], shl[64];
        int j = t & 63, rg = t >> 6;
        float ms = 0.f, m2 = 0.f;
        for (int k2 = rg; k2 < SB; k2 += 4) {
            ms += gs400[k2 * DIM + j];
            m2 += gq400[k2 * DIM + j];
        }
        red[t] = ms; red2[t] = m2;
        __syncthreads();
        if (t < 64) {
            ms = red[j] + red[64 + j] + red[128 + j] + red[192 + j];
            m2 = red2[j] + red2[64 + j] + red2[128 + j] + red2[192 + j];
            float mean = ms * (1.0f / N_NODES);
            float var  = m2 * (1.0f / N_NODES) - mean * mean;
            float inv  = 1.0f / sqrtf(var + BN_EPS);
            float sc   = bng[t] * inv;
            ssc[t] = sc;
            shl[t] = bnb[t] - mean * sc;
        }
        __syncthreads();
        if (t < 64) {
            float s = 0.f;
            for (int k2 = 0; k2 < DIM; k2++) s += shl[k2] * W1[k2 * DIM + t];
            cshift[t] = s;
        }
        for (int z = t; z < 4096; z += 256) Wsc[z] = W1[z] * ssc[z >> 6];
        for (int z = t; z < 2 * NSLOT * DIM; z += 256) gsum32[z] = 0.f;
        return;
    }
    __shared__ int ls[256];
    int i = blockIdx.x * 256 + t;
    int v = bh[i];
    ls[t] = v;
    __syncthreads();
    for (int off = 1; off < 256; off <<= 1) {
        int tv = (t >= off) ? ls[t - off] : 0;
        __syncthreads();
        ls[t] += tv;
        __syncthreads();
    }
    iscan[i] = ls[t];
    if (t == 255) bsum[blockIdx.x] = ls[255];
}

// ---------------- pass 1b: scatter packed {src<<8|dstlow} into bucket-major tmp ---------
__global__ __launch_bounds__(256) void k_p1scat(const int* __restrict__ ei,
                                                const int* __restrict__ bh,
                                                const int* __restrict__ iscan,
                                                const int* __restrict__ bsum,
                                                int* __restrict__ tmp) {
    __shared__ int cur[NB];
    __shared__ int s0[256], s1[256];
    int t = threadIdx.x, blk = blockIdx.x;
    int v0 = bsum[t];
    int v1 = (t < NB - 256) ? bsum[256 + t] : 0;
    s0[t] = v0; s1[t] = v1;
    __syncthreads();
    for (int off = 1; off < 256; off <<= 1) {
        int a0 = (t >= off) ? s0[t - off] : 0;
        int a1 = (t >= off) ? s1[t - off] : 0;
        __syncthreads();
        s0[t] += a0; s1[t] += a1;
        __syncthreads();
    }
    int carry = s0[255];
    {
        int i = t * P1B + blk;
        cur[t] = (s0[t] - v0) + iscan[i] - bh[i];          // boff[b]=excl prefix
    }
    if (t < NB - 256) {
        int b = 256 + t;
        int i = b * P1B + blk;
        cur[b] = (carry + s1[t] - v1) + iscan[i] - bh[i];
    }
    __syncthreads();
    int e0 = blk * P1E;
    for (int e = e0 + t; e < e0 + P1E; e += 256) {
        int r = ei[e], c = ei[N_EDGES + e];
        int pos = atomicAdd(&cur[c >> 8], 1);
        tmp[pos] = (r << 8) | (c & 255);
    }
}

// ---------------- pass 2 (fused): hist -> rowstart/dinv/winnode -> scatter --------------
__global__ __launch_bounds__(256) void k_p2(const int* __restrict__ tmp,
                                            const int* __restrict__ bsum,
                                            int* __restrict__ rowstart,
                                            float* __restrict__ dinv,
                                            int* __restrict__ winnode,
                                            float* __restrict__ C,
                                            int* __restrict__ csr) {
    int b = blockIdx.x, t = threadIdx.x;
    __shared__ int red[256];
    int part = 0;
    for (int k2 = t; k2 < b; k2 += 256) part += bsum[k2];
    red[t] = part;
    __syncthreads();
    for (int off = 128; off; off >>= 1) {
        if (t < off) red[t] += red[t + off];
        __syncthreads();
    }
    int bstart = red[0];
    int bend = bstart + bsum[b];
    __shared__ int cnt[256], scn[256], curs[256];
    cnt[t] = 0;
    __syncthreads();
    for (int e = bstart + t; e < bend; e += 256)
        atomicAdd(&cnt[tmp[e] & 255], 1);
    __syncthreads();
    scn[t] = cnt[t];
    __syncthreads();
    for (int off = 1; off < 256; off <<= 1) {
        int v = (t >= off) ? scn[t - off] : 0;
        __syncthreads();
        scn[t] += v;
        __syncthreads();
    }
    int node = b * 256 + t;
    int deg = cnt[t];
    int rs = bstart + scn[t] - deg;
    bool span = false;
    if (node <= N_NODES) rowstart[node] = rs;
    if (node == N_NODES) rowstart[node + 1] = rs;   // sentinel for per-lane preload
    if (node < N_NODES) {
        dinv[node] = 1.0f / sqrtf((float)(deg + 1));
        int re = rs + deg;
        for (int w = (rs + WIN - 1) / WIN; w * WIN < re; ++w) winnode[w] = node;
        span = (deg > 0) && (rs / WIN != (re - 1) / WIN);
    }
    // zero C rows of straddler nodes (wave-cooperative: 64 lanes write one row)
    int lane = t & 63;
    int wbase = b * 256 + (t & ~63);
    unsigned long long m = __ballot(span);
    while (m) {
        int bit = __builtin_ctzll(m);
        m &= m - 1;
        C[(size_t)(wbase + bit) * DIM + lane] = 0.f;
    }
    // within-bucket scatter -> final CSR (tmp segment is L1-hot from the histogram pass)
    curs[t] = rs;
    __syncthreads();
    for (int e = bstart + t; e < bend; e += 256) {
        int rec = tmp[e];
        int pos = atomicAdd(&curs[rec & 255], 1);
        csr[pos] = (int)((unsigned)rec >> 8);
    }
}

// ---------------- BN fold (layer 2): reduce 32 slots -> Wsc/cshift, re-zero slots -------
__global__ void k_bnfold(float* __restrict__ gsum, float* __restrict__ gsumsq,
                         const float* __restrict__ g, const float* __restrict__ b,
                         const float* __restrict__ W,
                         float* __restrict__ Wsc, float* __restrict__ cshift) {
    int j = threadIdx.x;
    float ms = 0.f, m2 = 0.f;
    for (int k = 0; k < NSLOT; k++) {
        ms += gsum[k * DIM + j];   gsum[k * DIM + j] = 0.f;
        m2 += gsumsq[k * DIM + j]; gsumsq[k * DIM + j] = 0.f;
    }
    float mean = ms * (1.0f / N_NODES);
    float var  = m2 * (1.0f / N_NODES) - mean * mean;
    float inv  = 1.0f / sqrtf(var + BN_EPS);
    float sc   = g[j] * inv;
    __shared__ float ssc[64], shl[64];
    ssc[j] = sc;
    shl[j] = b[j] - mean * sc;
    __syncthreads();
    float s = 0.f;
    for (int k = 0; k < DIM; k++) s += shl[k] * W[k * DIM + j];
    cshift[j] = s;
    for (int z = j; z < 4096; z += 64) Wsc[z] = W[z] * ssc[z >> 6];
}

// ---------------- GEMM (fp32 A): T' = (X@Wsc + cshift)*dinv[row], bf16 ------------------
// W via scalar loads (wave-uniform addr); A-stage loads vectorized to float4.
__global__ __launch_bounds__(256) void k_gemm_f32(const float* __restrict__ X,
                                                  const float* __restrict__ Wsc,
                                                  const float* __restrict__ cshift,
                                                  const float* __restrict__ dinv,
                                                  unsigned short* __restrict__ T) {
    __shared__ float Al[64 * 65];
    int row0 = blockIdx.x * 64;
    for (int t4 = threadIdx.x; t4 < 1024; t4 += 256) {
        int r = t4 >> 4, k4 = (t4 & 15) * 4;
        int i = row0 + r;
        float4 v = make_float4(0.f, 0.f, 0.f, 0.f);
        if (i < N_NODES) v = *(const float4*)&X[(size_t)i * DIM + k4];
        float* al = &Al[r * 65 + k4];
        al[0] = v.x; al[1] = v.y; al[2] = v.z; al[3] = v.w;
    }
    __syncthreads();
    int r = threadIdx.x & 63;
    int qu = __builtin_amdgcn_readfirstlane(threadIdx.x >> 6);
    float acc[16];
    #pragma unroll
    for (int jj = 0; jj < 16; jj++) acc[jj] = cshift[qu * 16 + jj];
    #pragma unroll 4
    for (int k = 0; k < 64; k++) {
        float a = Al[r * 65 + k];
        const float4* wv = (const float4*)(Wsc + (k << 6) + (qu << 4));
        float4 w0 = wv[0], w1 = wv[1], w2 = wv[2], w3 = wv[3];
        acc[0]  += a * w0.x; acc[1]  += a * w0.y; acc[2]  += a * w0.z; acc[3]  += a * w0.w;
        acc[4]  += a * w1.x; acc[5]  += a * w1.y; acc[6]  += a * w1.z; acc[7]  += a * w1.w;
        acc[8]  += a * w2.x; acc[9]  += a * w2.y; acc[10] += a * w2.z; acc[11] += a * w2.w;
        acc[12] += a * w3.x; acc[13] += a * w3.y; acc[14] += a * w3.z; acc[15] += a * w3.w;
    }
    int i = row0 + r;
    if (i < N_NODES) {
        float dv = dinv[i];
        unsigned int pk[8];
        #pragma unroll
        for (int jj = 0; jj < 8; jj++)
            pk[jj] = bf16_rtn2(acc[2 * jj] * dv, acc[2 * jj + 1] * dv);
        uint4* outv = (uint4*)&T[(size_t)i * DIM + qu * 16];
        outv[0] = make_uint4(pk[0], pk[1], pk[2], pk[3]);
        outv[1] = make_uint4(pk[4], pk[5], pk[6], pk[7]);
    }
}

// ---------------- GEMM (bf16 A): T' = (H@Wsc + cshift)*dinv[row], bf16 ------------------
// Blocks < N_GRAPHS also zero their pool row. A-stage loads vectorized (8 bf16).
__global__ __launch_bounds__(256) void k_gemm_b16(const unsigned short* __restrict__ X,
                                                  const float* __restrict__ Wsc,
                                                  const float* __restrict__ cshift,
                                                  const float* __restrict__ dinv,
                                                  unsigned short* __restrict__ T,
                                                  float* __restrict__ pool) {
    if (blockIdx.x < N_GRAPHS && threadIdx.x < 64)
        pool[(size_t)blockIdx.x * DIM + threadIdx.x] = 0.f;
    __shared__ float Al[64 * 65];
    int row0 = blockIdx.x * 64;
    for (int t8 = threadIdx.x; t8 < 512; t8 += 256) {
        int r = t8 >> 3, k8 = (t8 & 7) * 8;
        int i = row0 + r;
        uint4 v = make_uint4(0u, 0u, 0u, 0u);
        if (i < N_NODES) v = *(const uint4*)&X[(size_t)i * DIM + k8];
        float* al = &Al[r * 65 + k8];
        al[0] = blo(v.x); al[1] = bhi(v.x);
        al[2] = blo(v.y); al[3] = bhi(v.y);
        al[4] = blo(v.z); al[5] = bhi(v.z);
        al[6] = blo(v.w); al[7] = bhi(v.w);
    }
    __syncthreads();
    int r = threadIdx.x & 63;
    int qu = __builtin_amdgcn_readfirstlane(threadIdx.x >> 6);
    float acc[16];
    #pragma unroll
    for (int jj = 0; jj < 16; jj++) acc[jj] = cshift[qu * 16 + jj];
    #pragma unroll 4
    for (int k = 0; k < 64; k++) {
        float a = Al[r * 65 + k];
        const float4* wv = (const float4*)(Wsc + (k << 6) + (qu << 4));
        float4 w0 = wv[0], w1 = wv[1], w2 = wv[2], w3 = wv[3];
        acc[0]  += a * w0.x; acc[1]  += a * w0.y; acc[2]  += a * w0.z; acc[3]  += a * w0.w;
        acc[4]  += a * w1.x; acc[5]  += a * w1.y; acc[6]  += a * w1.z; acc[7]  += a * w1.w;
        acc[8]  += a * w2.x; acc[9]  += a * w2.y; acc[10] += a * w2.z; acc[11] += a * w2.w;
        acc[12] += a * w3.x; acc[13] += a * w3.y; acc[14] += a * w3.z; acc[15] += a * w3.w;
    }
    int i = row0 + r;
    if (i < N_NODES) {
        float dv = dinv[i];
        unsigned int pk[8];
        #pragma unroll
        for (int jj = 0; jj < 8; jj++)
            pk[jj] = bf16_rtn2(acc[2 * jj] * dv, acc[2 * jj + 1] * dv);
        uint4* outv = (uint4*)&T[(size_t)i * DIM + qu * 16];
        outv[0] = make_uint4(pk[0], pk[1], pk[2], pk[3]);
        outv[1] = make_uint4(pk[4], pk[5], pk[6], pk[7]);
    }
}

// ================= gather kernels (R15, unchanged: 64-lane atomics, WIN=128) ============
#define SWZ(V, S) __builtin_amdgcn_ds_swizzle((V), (((S) << 5) | 0x10))

#define ISSUE(SRCV, TVV, CV, S0) do {                                 \
    SRCV[0] = SWZ(CV, (S0) + 0); SRCV[1] = SWZ(CV, (S0) + 1);         \
    SRCV[2] = SWZ(CV, (S0) + 2); SRCV[3] = SWZ(CV, (S0) + 3);         \
    TVV[0] = T2[(unsigned)SRCV[0] * 16u + cc];                        \
    TVV[1] = T2[(unsigned)SRCV[1] * 16u + cc];                        \
    TVV[2] = T2[(unsigned)SRCV[2] * 16u + cc];                        \
    TVV[3] = T2[(unsigned)SRCV[3] * 16u + cc];                        \
} while (0)

#define STEP(TVV, U, B, FL) do {                                      \
    const int ebs = e0 + 16 * (B) + 4 * (U);                          \
    uint2 tvv = TVV[U];                                               \
    float a0 = blo(tvv.x), a1 = bhi(tvv.x);                           \
    float a2 = blo(tvv.y), a3 = bhi(tvv.y);                           \
    if (re > ebs + 3) {                                               \
        acc0 += a0; acc1 += a1; acc2 += a2; acc3 += a3;               \
    } else {                                                          \
        int lo = ebs;                                                 \
        while (re <= ebs + 3) {                                       \
            int eg = ebs + gg;                                        \
            if (eg >= lo && eg < re) {                                \
                acc0 += a0; acc1 += a1; acc2 += a2; acc3 += a3;       \
            }                                                         \
            lo = re;                                                  \
            FL();                                                     \
        }                                                             \
        if (ebs + gg >= lo) {                                         \
            acc0 += a0; acc1 += a1; acc2 += a2; acc3 += a3;           \
        }                                                             \
    }                                                                 \
} while (0)

#define CONSUME(TVV, B, FL) do {                                      \
    STEP(TVV, 0, B, FL); STEP(TVV, 1, B, FL);                         \
    STEP(TVV, 2, B, FL); STEP(TVV, 3, B, FL);                         \
} while (0)

#define COMB4()                                                       \
    float t0 = acc0 + __shfl_xor(acc0, 16); t0 += __shfl_xor(t0, 32); \
    float t1 = acc1 + __shfl_xor(acc1, 16); t1 += __shfl_xor(t1, 32); \
    float t2 = acc2 + __shfl_xor(acc2, 16); t2 += __shfl_xor(t2, 32); \
    float t3 = acc3 + __shfl_xor(acc3, 16); t3 += __shfl_xor(t3, 32);

#define REDIST64(OUT, V0, V1, V2, V3)                                 \
    float _r0 = __shfl((V0), lane >> 2);                              \
    float _r1 = __shfl((V1), lane >> 2);                              \
    float _r2 = __shfl((V2), lane >> 2);                              \
    float _r3 = __shfl((V3), lane >> 2);                              \
    float OUT = (lane & 2) ? ((lane & 1) ? _r3 : _r2)                 \
                           : ((lane & 1) ? _r1 : _r0);

#define ADVANCE() do {                                                \
    acc0 = acc1 = acc2 = acc3 = 0.f;                                  \
    ++i; ++k;                                                         \
    if (k < 64) re = __builtin_amdgcn_readlane(rsv, k);               \
    else        re = __builtin_amdgcn_readfirstlane(rowstart[i + 1]); \
    tsv = T2[(unsigned)i * 16u + cc];                                 \
} while (0)

#define FLUSH1() do {                                                 \
    COMB4();                                                          \
    if (part) {                                                       \
        REDIST64(cv, t0, t1, t2, t3);                                 \
        atomicAdd(&C[(size_t)i * DIM + lane], cv);                    \
        part = false;                                                 \
    } else {                                                          \
        int cnt = i - i0;                                             \
        float di;                                                     \
        if (cnt < 64)                                                 \
            di = __int_as_float(                                      \
                __builtin_amdgcn_readlane(__float_as_int(dv), cnt));  \
        else di = dinv[i];                                            \
        float h0 = fmaxf((t0 + blo(tsv.x)) * di + bb.x, 0.f);         \
        float h1 = fmaxf((t1 + bhi(tsv.x)) * di + bb.y, 0.f);         \
        float h2 = fmaxf((t2 + blo(tsv.y)) * di + bb.z, 0.f);         \
        float h3 = fmaxf((t3 + bhi(tsv.y)) * di + bb.w, 0.f);         \
        if (lane < 16)                                                \
            ((uint2*)H)[(unsigned)i * 16u + cc] =                     \
                make_uint2(bf16_rtn2(h0, h1), bf16_rtn2(h2, h3));     \
        s0 += h0; s1 += h1; s2 += h2; s3 += h3;                       \
        q0 += h0 * h0; q1 += h1 * h1; q2 += h2 * h2; q3 += h3 * h3;   \
    }                                                                 \
    ADVANCE();                                                        \
} while (0)

__global__ __launch_bounds__(256) void k_gather1(const unsigned short* __restrict__ T,
                                                 const float* __restrict__ dinv,
                                                 const int* __restrict__ rowstart,
                                                 const int* __restrict__ winnode,
                                                 const int* __restrict__ csr,
                                                 const float* __restrict__ bias,
                                                 float* __restrict__ C,
                                                 unsigned short* __restrict__ H,
                                                 float* __restrict__ gsum,
                                                 float* __restrict__ gsumsq) {
    const int lane = threadIdx.x & 63;
    const int gg = lane >> 4;          // edge sub-slot 0..3
    const int cc = lane & 15;          // uint2 index: cols 4cc..4cc+3
    const int w = blockIdx.x * 4 + (threadIdx.x >> 6);
    const int e0 = w * WIN;
    const int eend = e0 + WIN;
    const uint2* T2 = (const uint2*)T;

    int csrv0 = csr[e0 + 4 * cc + gg];                    // permuted window csr (1st 64)
    int csrv1 = csr[e0 + 64 + 4 * cc + gg];               // (2nd 64)
    int i0 = __builtin_amdgcn_readfirstlane(winnode[w]);
    int rsv = rowstart[min(i0 + lane, N_NODES + 1)];      // per-lane rowstart cache
    float dv = dinv[min(i0 + lane, N_NODES - 1)];         // per-lane dinv cache
    uint2 tsv = T2[(unsigned)i0 * 16u + cc];              // self-row prefetch
    const float4 bb = ((const float4*)bias)[cc];

    int i = i0, k = 1;
    int re = __builtin_amdgcn_readlane(rsv, 1);
    bool part = __builtin_amdgcn_readlane(rsv, 0) < e0;
    float acc0 = 0.f, acc1 = 0.f, acc2 = 0.f, acc3 = 0.f;
    float s0 = 0.f, s1 = 0.f, s2 = 0.f, s3 = 0.f;
    float q0 = 0.f, q1 = 0.f, q2 = 0.f, q3 = 0.f;

    int srcA[4], srcB[4], srcC[4], srcD[4];
    uint2 tva[4], tvb[4], tvc[4], tvd[4];
    ISSUE(srcA, tva, csrv0, 0);
    ISSUE(srcB, tvb, csrv0, 4);
    ISSUE(srcC, tvc, csrv0, 8);
    ISSUE(srcD, tvd, csrv0, 12);
    CONSUME(tva, 0, FLUSH1);  ISSUE(srcA, tva, csrv1, 0);
    CONSUME(tvb, 1, FLUSH1);  ISSUE(srcB, tvb, csrv1, 4);
    CONSUME(tvc, 2, FLUSH1);  ISSUE(srcC, tvc, csrv1, 8);
    CONSUME(tvd, 3, FLUSH1);  ISSUE(srcD, tvd, csrv1, 12);
    CONSUME(tva, 4, FLUSH1);
    CONSUME(tvb, 5, FLUSH1);
    CONSUME(tvc, 6, FLUSH1);
    CONSUME(tvd, 7, FLUSH1);

    if (part || re > eend) {
        COMB4();
        REDIST64(cv, t0, t1, t2, t3);
        atomicAdd(&C[(size_t)i * DIM + lane], cv);
    } else {
        FLUSH1();
    }

    __shared__ float shs[4][64], shq[4][64];
    int wv = threadIdx.x >> 6;
    if (lane < 16) {
        shs[wv][4 * cc + 0] = s0; shs[wv][4 * cc + 1] = s1;
        shs[wv][4 * cc + 2] = s2; shs[wv][4 * cc + 3] = s3;
        shq[wv][4 * cc + 0] = q0; shq[wv][4 * cc + 1] = q1;
        shq[wv][4 * cc + 2] = q2; shq[wv][4 * cc + 3] = q3;
    }
    __syncthreads();
    if (threadIdx.x < 64) {
        int j = threadIdx.x;
        float vs = shs[0][j] + shs[1][j] + shs[2][j] + shs[3][j];
        float vq = shq[0][j] + shq[1][j] + shq[2][j] + shq[3][j];
        int slot = (blockIdx.x & (NSLOT - 1)) * DIM;
        atomicAdd(&gsum[slot + j], vs);
        atomicAdd(&gsumsq[slot + j], vq);
    }
}

#define FLUSH2() do {                                                 \
    COMB4();                                                          \
    if (part) {                                                       \
        REDIST64(cv, t0, t1, t2, t3);                                 \
        atomicAdd(&C[(size_t)i * DIM + lane], cv);                    \
        part = false;                                                 \
    } else {                                                          \
        int cnt = i - i0;                                             \
        float di;                                                     \
        int gi;                                                       \
        if (cnt < 64) {                                               \
            di = __int_as_float(                                      \
                __builtin_amdgcn_readlane(__float_as_int(dv), cnt));  \
            gi = __builtin_amdgcn_readlane(bv, cnt);                  \
        } else { di = dinv[i]; gi = batch[i]; }                       \
        float h0 = fmaxf((t0 + blo(tsv.x)) * di + bb.x, 0.f);         \
        float h1 = fmaxf((t1 + bhi(tsv.x)) * di + bb.y, 0.f);         \
        float h2 = fmaxf((t2 + blo(tsv.y)) * di + bb.z, 0.f);         \
        float h3 = fmaxf((t3 + bhi(tsv.y)) * di + bb.w, 0.f);         \
        s0 += h0; s1 += h1; s2 += h2; s3 += h3;                       \
        q0 += h0 * h0; q1 += h1 * h1; q2 += h2 * h2; q3 += h3 * h3;   \
        if (gi != cur_g) {                                            \
            if (cur_g >= 0) {                                         \
                REDIST64(pv, ps0, ps1, ps2, ps3);                     \
                atomicAdd(&pool[(size_t)cur_g * DIM + lane], pv);     \
            }                                                         \
            ps0 = ps1 = ps2 = ps3 = 0.f;                              \
            cur_g = gi;                                               \
        }                                                             \
        ps0 += h0; ps1 += h1; ps2 += h2; ps3 += h3;                   \
    }                                                                 \
    ADVANCE();                                                        \
} while (0)

__global__ __launch_bounds__(256) void k_gather2(const unsigned short* __restrict__ T,
                                                 const float* __restrict__ dinv,
                                                 const int* __restrict__ rowstart,
                                                 const int* __restrict__ winnode,
                                                 const int* __restrict__ csr,
                                                 const float* __restrict__ bias,
                                                 const int* __restrict__ batch,
                                                 float* __restrict__ C,
                                                 float* __restrict__ pool,
                                                 float* __restrict__ gsum,
                                                 float* __restrict__ gsumsq) {
    const int lane = threadIdx.x & 63;
    const int gg = lane >> 4;
    const int cc = lane & 15;
    const int w = blockIdx.x * 4 + (threadIdx.x >> 6);
    const int e0 = w * WIN;
    const int eend = e0 + WIN;
    const uint2* T2 = (const uint2*)T;

    int csrv0 = csr[e0 + 4 * cc + gg];
    int csrv1 = csr[e0 + 64 + 4 * cc + gg];
    int i0 = __builtin_amdgcn_readfirstlane(winnode[w]);
    int rsv = rowstart[min(i0 + lane, N_NODES + 1)];
    float dv = dinv[min(i0 + lane, N_NODES - 1)];
    int bv = batch[min(i0 + lane, N_NODES - 1)];
    uint2 tsv = T2[(unsigned)i0 * 16u + cc];
    const float4 bb = ((const float4*)bias)[cc];

    int i = i0, k = 1;
    int re = __builtin_amdgcn_readlane(rsv, 1);
    bool part = __builtin_amdgcn_readlane(rsv, 0) < e0;
    float acc0 = 0.f, acc1 = 0.f, acc2 = 0.f, acc3 = 0.f;
    float s0 = 0.f, s1 = 0.f, s2 = 0.f, s3 = 0.f;
    float q0 = 0.f, q1 = 0.f, q2 = 0.f, q3 = 0.f;
    float ps0 = 0.f, ps1 = 0.f, ps2 = 0.f, ps3 = 0.f;
    int cur_g = -1;

    int srcA[4], srcB[4], srcC[4], srcD[4];
    uint2 tva[4], tvb[4], tvc[4], tvd[4];
    ISSUE(srcA, tva, csrv0, 0);
    ISSUE(srcB, tvb, csrv0, 4);
    ISSUE(srcC, tvc, csrv0, 8);
    ISSUE(srcD, tvd, csrv0, 12);
    CONSUME(tva, 0, FLUSH2);  ISSUE(srcA, tva, csrv1, 0);
    CONSUME(tvb, 1, FLUSH2);  ISSUE(srcB, tvb, csrv1, 4);
    CONSUME(tvc, 2, FLUSH2);  ISSUE(srcC, tvc, csrv1, 8);
    CONSUME(tvd, 3, FLUSH2);  ISSUE(srcD, tvd, csrv1, 12);
    CONSUME(tva, 4, FLUSH2);
    CONSUME(tvb, 5, FLUSH2);
    CONSUME(tvc, 6, FLUSH2);
    CONSUME(tvd, 7, FLUSH2);

    if (part || re > eend) {
        COMB4();
        REDIST64(cv, t0, t1, t2, t3);
        atomicAdd(&C[(size_t)i * DIM + lane], cv);
    } else {
        FLUSH2();
    }
    if (cur_g >= 0) {
        REDIST64(pv, ps0, ps1, ps2, ps3);
        atomicAdd(&pool[(size_t)cur_g * DIM + lane], pv);
    }

    __shared__ float shs[4][64], shq[4][64];
    int wv = threadIdx.x >> 6;
    if (lane < 16) {
        shs[wv][4 * cc + 0] = s0; shs[wv][4 * cc + 1] = s1;
        shs[wv][4 * cc + 2] = s2; shs[wv][4 * cc + 3] = s3;
        shq[wv][4 * cc + 0] = q0; shq[wv][4 * cc + 1] = q1;
        shq[wv][4 * cc + 2] = q2; shq[wv][4 * cc + 3] = q3;
    }
    __syncthreads();
    if (threadIdx.x < 64) {
        int j = threadIdx.x;
        float vs = shs[0][j] + shs[1][j] + shs[2][j] + shs[3][j];
        float vq = shq[0][j] + shq[1][j] + shq[2][j] + shq[3][j];
        int slot = (blockIdx.x & (NSLOT - 1)) * DIM;
        atomicAdd(&gsum[slot + j], vs);
        atomicAdd(&gsumsq[slot + j], vq);
    }
}

// ---------------- straddler + boundary-deg0 finish, layer 1 (-> H + stats) --------------
__global__ __launch_bounds__(256) void k_strad1(float* __restrict__ C,
                                                const unsigned short* __restrict__ T,
                                                const float* __restrict__ dinv,
                                                const int* __restrict__ rowstart,
                                                const int* __restrict__ winnode,
                                                const float* __restrict__ bias,
                                                unsigned short* __restrict__ H,
                                                float* __restrict__ gsum,
                                                float* __restrict__ gsumsq) {
    int lane = threadIdx.x & 63;
    int wv = threadIdx.x >> 6;
    float bb = bias[lane];
    float s = 0.f, s2 = 0.f;
    __shared__ int anyw;
    if (threadIdx.x == 0) anyw = 0;
    __syncthreads();
    if (blockIdx.x < NWIN / 4) {
        int w = blockIdx.x * 4 + wv;
        int n = winnode[w];
        int rs = rowstart[n];
        if (w == rs / WIN + 1) {
            float di = dinv[n];
            float c = C[(size_t)n * DIM + lane];
            C[(size_t)n * DIM + lane] = 0.f;        // re-zero for layer 2
            float h = fmaxf((c + bfup(T[(size_t)n * DIM + lane])) * di + bb, 0.f);
            H[(size_t)n * DIM + lane] = bf16r(h);
            s += h; s2 += h * h;
            anyw = 1;
        }
    } else {
        int base = (blockIdx.x - NWIN / 4) * 256 + wv * 64;
        int nb = base + lane;
        int d0 = 0;
        if (nb < N_NODES)
            d0 = (rowstart[nb + 1] == rowstart[nb]) && ((rowstart[nb] & (WIN - 1)) == 0);
        unsigned long long m = __ballot(d0);
        while (m) {
            int b = __builtin_ctzll(m);
            m &= m - 1;
            int n = base + b;
            float di = dinv[n];
            float h = fmaxf(bfup(T[(size_t)n * DIM + lane]) * di + bb, 0.f);
            H[(size_t)n * DIM + lane] = bf16r(h);
            s += h; s2 += h * h;
            anyw = 1;
        }
    }
    __shared__ float ls[256], ls2[256];
    ls[threadIdx.x] = s; ls2[threadIdx.x] = s2;
    __syncthreads();
    if (anyw && threadIdx.x < 64) {
        int j = threadIdx.x;
        int slot = (blockIdx.x & (NSLOT - 1)) * DIM;
        atomicAdd(&gsum[slot + j],   ls[j] + ls[64 + j] + ls[128 + j] + ls[192 + j]);
        atomicAdd(&gsumsq[slot + j], ls2[j] + ls2[64 + j] + ls2[128 + j] + ls2[192 + j]);
    }
}

// ---------------- straddler + boundary-deg0 finish, layer 2 (-> pool + stats) -----------
__global__ __launch_bounds__(256) void k_strad2(const float* __restrict__ C,
                                                const unsigned short* __restrict__ T,
                                                const float* __restrict__ dinv,
                                                const int* __restrict__ rowstart,
                                                const int* __restrict__ winnode,
                                                const float* __restrict__ bias,
                                                const int* __restrict__ batch,
                                                float* __restrict__ pool,
                                                float* __restrict__ gsum,
                                                float* __restrict__ gsumsq) {
    int lane = threadIdx.x & 63;
    int wv = threadIdx.x >> 6;
    float bb = bias[lane];
    float s = 0.f, s2 = 0.f;
    __shared__ int anyw;
    if (threadIdx.x == 0) anyw = 0;
    __syncthreads();
    if (blockIdx.x < NWIN / 4) {
        int w = blockIdx.x * 4 + wv;
        int n = winnode[w];
        int rs = rowstart[n];
        if (w == rs / WIN + 1) {
            float di = dinv[n];
            float h = fmaxf((C[(size_t)n * DIM + lane]
                             + bfup(T[(size_t)n * DIM + lane])) * di + bb, 0.f);
            s += h; s2 += h * h;
            atomicAdd(&pool[(size_t)batch[n] * DIM + lane], h);
            anyw = 1;
        }
    } else {
        int base = (blockIdx.x - NWIN / 4) * 256 + wv * 64;
        int nb = base + lane;
        int d0 = 0;
        if (nb < N_NODES)
            d0 = (rowstart[nb + 1] == rowstart[nb]) && ((rowstart[nb] & (WIN - 1)) == 0);
        unsigned long long m = __ballot(d0);
        while (m) {
            int b = __builtin_ctzll(m);
            m &= m - 1;
            int n = base + b;
            float di = dinv[n];
            float h = fmaxf(bfup(T[(size_t)n * DIM + lane]) * di + bb, 0.f);
            s += h; s2 += h * h;
            atomicAdd(&pool[(size_t)batch[n] * DIM + lane], h);
            anyw = 1;
        }
    }
    __shared__ float ls[256], ls2[256];
    ls[threadIdx.x] = s; ls2[threadIdx.x] = s2;
    __syncthreads();
    if (anyw && threadIdx.x < 64) {
        int j = threadIdx.x;
        int slot = (blockIdx.x & (NSLOT - 1)) * DIM;
        atomicAdd(&gsum[slot + j],   ls[j] + ls[64 + j] + ls[128 + j] + ls[192 + j]);
        atomicAdd(&gsumsq[slot + j], ls2[j] + ls2[64 + j] + ls2[128 + j] + ls2[192 + j]);
    }
}

// ---------------- final (fused BN2 fold): per-block scale/shift from 32 slots -----------
__global__ void k_final(const float* __restrict__ pool, const int* __restrict__ start,
                        const float* __restrict__ gsum, const float* __restrict__ gsumsq,
                        const float* __restrict__ g, const float* __restrict__ be,
                        const float* __restrict__ Wout, const float* __restrict__ bout,
                        float* __restrict__ out) {
    int gr = blockIdx.x;
    int l = threadIdx.x;
    float ms = 0.f, m2 = 0.f;
    for (int k = 0; k < NSLOT; k++) { ms += gsum[k * DIM + l]; m2 += gsumsq[k * DIM + l]; }
    float mean = ms * (1.0f / N_NODES);
    float var  = m2 * (1.0f / N_NODES) - mean * mean;
    float inv  = 1.0f / sqrtf(var + BN_EPS);
    float sc   = g[l] * inv;
    float sh   = be[l] - mean * sc;
    float c = fmaxf((float)(start[gr + 1] - start[gr]), 1.f);
    float p = (pool[gr * DIM + l] / c) * sc + sh;
    float a0 = p * Wout[l * 2 + 0];
    float a1 = p * Wout[l * 2 + 1];
    #pragma unroll
    for (int off = 32; off; off >>= 1) {
        a0 += __shfl_down(a0, off, 64);
        a1 += __shfl_down(a1, off, 64);
    }
    if (l == 0) {
        out[gr * 2 + 0] = a0 + bout[0];
        out[gr * 2 + 1] = a1 + bout[1];
    }
}

extern "C" void kernel_launch(void* const* d_in, const int* in_sizes, int n_in,
                              void* d_out, int out_size, void* d_ws, size_t ws_size,
                              hipStream_t stream) {
    (void)in_sizes; (void)n_in; (void)out_size; (void)ws_size;
    const float* x       = (const float*)d_in[0];
    const int*   ei      = (const int*)d_in[1];
    const int*   batch   = (const int*)d_in[2];
    const float* bn_in_g = (const float*)d_in[3];
    const float* bn_in_b = (const float*)d_in[4];
    const float* W1      = (const float*)d_in[5];
    const float* b1      = (const float*)d_in[6];
    const float* g1      = (const float*)d_in[7];
    const float* be1     = (const float*)d_in[8];
    const float* W2      = (const float*)d_in[9];
    const float* b2      = (const float*)d_in[10];
    const float* g2      = (const float*)d_in[11];
    const float* be2     = (const float*)d_in[12];
    const float* Wout    = (const float*)d_in[13];
    const float* bout    = (const float*)d_in[14];
    float* out = (float*)d_out;

    // workspace layout (~60 MB); all offsets kept 16B-aligned for float4 global reads
    char* p = (char*)d_ws;
    float* C = (float*)p;                   p += (size_t)N_NODES * DIM * 4;  // 25.6 MB
    unsigned short* H = (unsigned short*)p; p += (size_t)N_NODES * DIM * 2;  // 12.8 MB
    unsigned short* T = (unsigned short*)p; p += (size_t)N_NODES * DIM * 2;  // 12.8 MB
    int* csr = (int*)p;                     p += (size_t)N_EDGES * 4;        // 5.12 MB
    float* dinv = (float*)p;                p += N_NODES * 4;
    int* bh = (int*)p;                      p += NB * P1B * 4;
    int* iscan = (int*)p;                   p += NB * P1B * 4;
    int* rowstart = (int*)p;                p += (N_NODES + 4) * 4;          // 16B-pad
    int* winnode = (int*)p;                 p += NWIN * 4;
    int* bsum = (int*)p;                    p += NB * 4;
    int* start = (int*)p;                   p += (N_GRAPHS + 4) * 4;         // 16B-pad
    float* gsum32 = (float*)p;              p += NSLOT * DIM * 4;            // atomic slots
    float* gsumsq32 = (float*)p;            p += NSLOT * DIM * 4;            // (contiguous)
    float* gs400 = (float*)p;               p += (size_t)SB * DIM * 4;       // input stats
    float* gq400 = (float*)p;               p += (size_t)SB * DIM * 4;
    float* Wsc = (float*)p;                 p += 4096 * 4;                   // scaled W
    float* cshift = (float*)p;              p += DIM * 4;
    float* pool = (float*)p;                p += (size_t)N_GRAPHS * DIM * 4;
    int* tmp = (int*)H;   // packed bucket-sort temp aliases H (dead before gather1 writes H)

    // ---- CSR build + BN-input stats + graph boundaries ----
    k_p1hist<<<P1B + SB + 392, 256, 0, stream>>>(ei, batch, x, bh, start, gs400, gq400);
    k_scan1<<<NB + 1, 256, 0, stream>>>(bh, iscan, bsum, gs400, gq400,
                                        bn_in_g, bn_in_b, W1, Wsc, cshift, gsum32);
    k_p1scat<<<P1B, 256, 0, stream>>>(ei, bh, iscan, bsum, tmp);
    k_p2<<<NB, 256, 0, stream>>>(tmp, bsum, rowstart, dinv, winnode, C, csr);

    // ---- GEMM1 (scalar-W) -> gather1 -> straddle ----
    k_gemm_f32<<<(N_NODES + 63) / 64, 256, 0, stream>>>(x, Wsc, cshift, dinv, T);
    k_gather1<<<NWIN / 4, 256, 0, stream>>>(T, dinv, rowstart, winnode, csr, b1,
                                            C, H, gsum32, gsumsq32);
    k_strad1<<<NWIN / 4 + 392, 256, 0, stream>>>(C, T, dinv, rowstart, winnode, b1,
                                                 H, gsum32, gsumsq32);

    // ---- BN1 fold (writes Wsc for layer 2) -> GEMM2 (+pool zero) -> gather2 -> straddle
    k_bnfold<<<1, 64, 0, stream>>>(gsum32, gsumsq32, g1, be1, W2, Wsc, cshift);
    k_gemm_b16<<<(N_NODES + 63) / 64, 256, 0, stream>>>(H, Wsc, cshift, dinv, T, pool);
    k_gather2<<<NWIN / 4, 256, 0, stream>>>(T, dinv, rowstart, winnode, csr, b2,
                                            batch, C, pool, gsum32, gsumsq32);
    k_strad2<<<NWIN / 4 + 392, 256, 0, stream>>>(C, T, dinv, rowstart, winnode, b2,
                                                 batch, pool, gsum32, gsumsq32);

    // ---- final (BN2 fold fused per-block) ----
    k_final<<<N_GRAPHS, 64, 0, stream>>>(pool, start, gsum32, gsumsq32, g2, be2,
                                         Wout, bout, out);
}